// Round 1
// baseline (1164.103 us; speedup 1.0000x reference)
//
#include <hip/hip_runtime.h>
#include <math.h>

#define NBINS 255
#define BIN_LO_F (-20.0f)
#define BIN_HI_F (20.0f)
#define TM 32
#define BK 32

__device__ __forceinline__ double wave_reduce_sum_d(double v) {
    #pragma unroll
    for (int m = 32; m >= 1; m >>= 1) v += __shfl_xor(v, m, 64);
    return v;
}

// Kernel 1: logits = [latents; bootstrap] @ W + b  -> (R, 255) fp32 in ws
__global__ __launch_bounds__(256) void gemm_logits(
    const float* __restrict__ latents,   // (NR, D)
    const float* __restrict__ boot,      // (B, D)
    const float* __restrict__ W,         // (D, 255)
    const float* __restrict__ bvec,      // (255)
    float* __restrict__ logits,          // (R, 255)
    int NR, int R, int D)
{
    __shared__ float As[TM][BK + 4];
    __shared__ float Ws[BK * NBINS + 32];   // linear [k*255 + j], +pad for the harmless j==255 over-read

    const int tid = threadIdx.x;
    const int tb  = tid & 31;    // bin lane 0..31
    const int rg  = tid >> 5;    // row group 0..7 (4 rows each)
    const int row0 = blockIdx.x * TM;

    float acc[4][8];
    #pragma unroll
    for (int r = 0; r < 4; ++r)
        #pragma unroll
        for (int i = 0; i < 8; ++i) acc[r][i] = 0.f;

    const int arow = tid >> 3;   // 0..31 (row within tile for A loads)
    const int aq   = tid & 7;    // 0..7  (16B chunk within BK)
    int grow = row0 + arow; if (grow > R - 1) grow = R - 1;
    const float* aptr = (grow < NR) ? (latents + (size_t)grow * D)
                                    : (boot + (size_t)(grow - NR) * D);

    const float4* __restrict__ Wg4base = reinterpret_cast<const float4*>(W);
    float4* Ws4 = reinterpret_cast<float4*>(Ws);

    for (int k0 = 0; k0 < D; k0 += BK) {
        // prefetch into registers (overlaps previous compute)
        float4 av = *reinterpret_cast<const float4*>(aptr + k0 + aq * 4);
        float4 wreg[8];
        const float4* Wg4 = Wg4base + ((size_t)k0 * NBINS) / 4;
        #pragma unroll
        for (int e = 0; e < 8; ++e) {
            int idx = tid + e * 256;                 // float4 index, total 2040
            if (idx < (BK * NBINS) / 4) wreg[e] = Wg4[idx];
        }

        __syncthreads();   // previous compute done before overwriting LDS
        *reinterpret_cast<float4*>(&As[arow][aq * 4]) = av;
        #pragma unroll
        for (int e = 0; e < 8; ++e) {
            int idx = tid + e * 256;
            if (idx < (BK * NBINS) / 4) Ws4[idx] = wreg[e];
        }
        __syncthreads();

        #pragma unroll 4
        for (int k = 0; k < BK; ++k) {
            float a0 = As[rg * 4 + 0][k];
            float a1 = As[rg * 4 + 1][k];
            float a2 = As[rg * 4 + 2][k];
            float a3 = As[rg * 4 + 3][k];
            float w[8];
            #pragma unroll
            for (int i = 0; i < 8; ++i) w[i] = Ws[k * NBINS + tb + 32 * i];
            #pragma unroll
            for (int i = 0; i < 8; ++i) {
                acc[0][i] = fmaf(a0, w[i], acc[0][i]);
                acc[1][i] = fmaf(a1, w[i], acc[1][i]);
                acc[2][i] = fmaf(a2, w[i], acc[2][i]);
                acc[3][i] = fmaf(a3, w[i], acc[3][i]);
            }
        }
    }

    #pragma unroll
    for (int i = 0; i < 8; ++i) {
        int j = tb + 32 * i;
        if (j < NBINS) {
            float bj = bvec[j];
            #pragma unroll
            for (int r = 0; r < 4; ++r) {
                int row = row0 + rg * 4 + r;
                if (row < R) logits[(size_t)row * NBINS + j] = acc[r][i] + bj;
            }
        }
    }
}

// Kernel 2: per-row softmax stats: value = softmax(l)@centers, logZ
__global__ __launch_bounds__(256) void softmax_stats(
    const float* __restrict__ logits, float* __restrict__ values,
    float* __restrict__ logZ, int R)
{
    int row  = blockIdx.x * 4 + (threadIdx.x >> 6);
    int lane = threadIdx.x & 63;
    if (row >= R) return;
    const float* lp = logits + (size_t)row * NBINS;
    const float step = (float)(40.0 / 254.0);

    float l[4];
    float m = -INFINITY;
    #pragma unroll
    for (int u = 0; u < 4; ++u) {
        int idx = lane + 64 * u;
        l[u] = (idx < NBINS) ? lp[idx] : -INFINITY;
        m = fmaxf(m, l[u]);
    }
    #pragma unroll
    for (int sh = 32; sh >= 1; sh >>= 1) m = fmaxf(m, __shfl_xor(m, sh, 64));

    float s = 0.f, sc = 0.f;
    #pragma unroll
    for (int u = 0; u < 4; ++u) {
        int idx = lane + 64 * u;
        if (idx < NBINS) {
            float e = __expf(l[u] - m);
            s  += e;
            sc += e * (BIN_LO_F + step * (float)idx);
        }
    }
    #pragma unroll
    for (int sh = 32; sh >= 1; sh >>= 1) {
        s  += __shfl_xor(s, sh, 64);
        sc += __shfl_xor(sc, sh, 64);
    }
    if (lane == 0) {
        values[row] = sc / s;
        logZ[row]   = m + __logf(s);
    }
}

// Kernel 3: backward lambda-return recurrence, one thread per batch row
__global__ void lambda_returns_k(
    const float* __restrict__ rewards, const float* __restrict__ dones,
    const float* __restrict__ values, float* __restrict__ returns,
    int B, int H, int NR)
{
    int b = blockIdx.x * blockDim.x + threadIdx.x;
    if (b >= B) return;
    const float gamma = 0.997f;
    const float lam   = 0.95f;
    const float oml   = (float)(1.0 - 0.95);
    float bootv = values[NR + b];
    float g = bootv;
    for (int h = H - 1; h >= 0; --h) {
        float nv   = (h == H - 1) ? bootv : values[b * H + h + 1];
        float mask = 1.0f - dones[b * H + h];
        g = rewards[b * H + h] + gamma * mask * (oml * nv + lam * g);
        returns[b * H + h] = g;
    }
}

// Kernel 4: two-hot CE loss + moment sums (double accumulation)
__global__ __launch_bounds__(256) void loss_moments(
    const float* __restrict__ logits, const float* __restrict__ logZ,
    const float* __restrict__ values, const float* __restrict__ returns,
    double* __restrict__ accum, int NR)
{
    int row = blockIdx.x * blockDim.x + threadIdx.x;
    double lsum = 0, vsum = 0, v2 = 0, rsum = 0, r2 = 0;
    if (row < NR) {
        float v   = values[row];
        float ret = returns[row];
        float cl  = fminf(fmaxf(ret, BIN_LO_F), BIN_HI_F);
        const float step = (float)(40.0 / 254.0);
        float pos = (cl - BIN_LO_F) / step;
        int low = (int)floorf(pos);
        low = min(max(low, 0), NBINS - 2);
        float frac = pos - (float)low;
        const float* lp = logits + (size_t)row * NBINS;
        float llo = lp[low], lhi = lp[low + 1];
        float loss = logZ[row] - (1.f - frac) * llo - frac * lhi;
        lsum = (double)loss;
        vsum = (double)v;   v2 = (double)v * (double)v;
        rsum = (double)ret; r2 = (double)ret * (double)ret;
    }
    lsum = wave_reduce_sum_d(lsum);
    vsum = wave_reduce_sum_d(vsum);
    v2   = wave_reduce_sum_d(v2);
    rsum = wave_reduce_sum_d(rsum);
    r2   = wave_reduce_sum_d(r2);
    if ((threadIdx.x & 63) == 0) {
        atomicAdd(&accum[0], lsum);
        atomicAdd(&accum[1], vsum);
        atomicAdd(&accum[2], v2);
        atomicAdd(&accum[3], rsum);
        atomicAdd(&accum[4], r2);
    }
}

// Kernel 5: finalize the 6 outputs
__global__ void finalize_k(const double* __restrict__ accum,
                           float* __restrict__ out, int NR)
{
    if (threadIdx.x == 0 && blockIdx.x == 0) {
        double n  = (double)NR;
        double vl = accum[0] / n;
        double mv = accum[1] / n;
        double vv = (accum[2] - n * mv * mv) / (n - 1.0);
        double mr = accum[3] / n;
        double vr = (accum[4] - n * mr * mr) / (n - 1.0);
        out[0] = (float)(0.5 * vl);
        out[1] = (float)vl;
        out[2] = (float)mv;
        out[3] = (float)mr;
        out[4] = (float)sqrt(vv > 0.0 ? vv : 0.0);
        out[5] = (float)sqrt(vr > 0.0 ? vr : 0.0);
    }
}

extern "C" void kernel_launch(void* const* d_in, const int* in_sizes, int n_in,
                              void* d_out, int out_size, void* d_ws, size_t ws_size,
                              hipStream_t stream) {
    const float* latents = (const float*)d_in[0];
    const float* rewards = (const float*)d_in[1];
    const float* dones   = (const float*)d_in[2];
    const float* boot    = (const float*)d_in[3];
    const float* W       = (const float*)d_in[4];
    const float* bvec    = (const float*)d_in[5];
    float* out = (float*)d_out;

    const int BH = in_sizes[1];          // B*H = 16384
    const int D  = in_sizes[0] / BH;     // 4096
    const int B  = in_sizes[3] / D;      // 1024
    const int H  = BH / B;               // 16
    const int NR = BH;
    const int R  = NR + B;               // 17408

    char* ws = (char*)d_ws;
    size_t off = 0;
    float* logits = (float*)(ws + off); off += (size_t)R * NBINS * sizeof(float);
    off = (off + 255) & ~(size_t)255;
    float* values = (float*)(ws + off); off += (size_t)R * sizeof(float);
    float* logZ   = (float*)(ws + off); off += (size_t)R * sizeof(float);
    float* rets   = (float*)(ws + off); off += (size_t)NR * sizeof(float);
    off = (off + 255) & ~(size_t)255;
    double* accum = (double*)(ws + off); off += 8 * sizeof(double);

    hipMemsetAsync(accum, 0, 8 * sizeof(double), stream);

    int nTiles = (R + TM - 1) / TM;
    gemm_logits<<<nTiles, 256, 0, stream>>>(latents, boot, W, bvec, logits, NR, R, D);
    softmax_stats<<<(R + 3) / 4, 256, 0, stream>>>(logits, values, logZ, R);
    lambda_returns_k<<<(B + 255) / 256, 256, 0, stream>>>(rewards, dones, values, rets, B, H, NR);
    loss_moments<<<(NR + 255) / 256, 256, 0, stream>>>(logits, logZ, values, rets, accum, NR);
    finalize_k<<<1, 64, 0, stream>>>(accum, out, NR);
}

// Round 2
// 272.847 us; speedup vs baseline: 4.2665x; 4.2665x over previous
//
#include <hip/hip_runtime.h>
#include <math.h>

#define NBINS 255
#define BIN_LO_F (-20.0f)
#define BIN_HI_F (20.0f)

typedef __attribute__((ext_vector_type(8))) short short8;
typedef __attribute__((ext_vector_type(16))) float f32x16;

__device__ __forceinline__ unsigned short f2bf(float f) {
    unsigned u = __builtin_bit_cast(unsigned, f);
    unsigned r = u + 0x7fffu + ((u >> 16) & 1u);
    return (unsigned short)(r >> 16);
}

__device__ __forceinline__ void glds16(const void* g, void* l) {
    __builtin_amdgcn_global_load_lds(
        (const __attribute__((address_space(1))) unsigned int*)g,
        (__attribute__((address_space(3))) unsigned int*)l, 16, 0, 0);
}

__device__ __forceinline__ double wave_reduce_sum_d(double v) {
    #pragma unroll
    for (int m = 32; m >= 1; m >>= 1) v += __shfl_xor(v, m, 64);
    return v;
}

// Pack W (D,255) fp32 -> Wpack bf16 in the exact per-K-step LDS image:
// flat short8 index t: col=t&255, chunk=(t>>8)&7, kstep=t>>11
// element e: k = kstep*64 + chunk*8 + e, j = col (col 255 zero pad)
__global__ __launch_bounds__(256) void pack_w(
    const float* __restrict__ W, char* __restrict__ Wpack)
{
    int t = blockIdx.x * 256 + threadIdx.x;
    int col = t & 255;
    int k0 = ((t >> 11) << 6) + (((t >> 8) & 7) << 3);
    short8 s;
    #pragma unroll
    for (int e = 0; e < 8; ++e)
        s[e] = (col < NBINS) ? (short)f2bf(W[(size_t)(k0 + e) * NBINS + col]) : (short)0;
    *(short8*)(Wpack + (size_t)t * 16) = s;
}

// MFMA GEMM: logits(R,255) = [latents; boot](R,4096) @ W + b, bf16 inputs fp32 acc.
// BM=64, BN=256 (all bins), BK=64, 256 threads = 4 waves, wave tile 64x64,
// v_mfma_f32_32x32x16_bf16, double-buffered LDS (80KB), A reg-staged fp32->bf16,
// B via global_load_lds from pre-packed Wpack.
__global__ __launch_bounds__(256, 2) void gemm_mfma(
    const float* __restrict__ latents, const float* __restrict__ boot,
    const char* __restrict__ Wpack, const float* __restrict__ bvec,
    float* __restrict__ logits, int NR, int R, int D)
{
    __shared__ __align__(16) char lds[81920];   // A: 2x8KB @0, B: 2x32KB @16384
    const int tid  = threadIdx.x;
    const int wave = tid >> 6, lane = tid & 63;
    const int l31  = lane & 31, lhi = lane >> 5;
    const int wcol = wave * 64;
    const int row0 = blockIdx.x * 64;
    const int NT   = D >> 6;

    // A staging role: thread covers row=tid>>2, k quarter=tid&3 (16 floats)
    const int arow = tid >> 2, akq = tid & 3;
    const int row_g = row0 + arow;
    const float* aptr = (row_g < NR) ? latents + (size_t)row_g * D
                                     : boot + (size_t)(row_g - NR) * D;
    aptr += akq * 16;

    f32x16 acc[2][2];
    #pragma unroll
    for (int i = 0; i < 2; ++i)
        #pragma unroll
        for (int j = 0; j < 2; ++j)
            #pragma unroll
            for (int r = 0; r < 16; ++r) acc[i][j][r] = 0.f;

    float af[2][16];

    // prologue: stage tile 0, prefetch A(1)
    #pragma unroll
    for (int q = 0; q < 4; ++q)
        *(float4*)&af[0][q * 4] = *(const float4*)(aptr + q * 4);
    {
        const char* wp = Wpack;
        char* Bb = lds + 16384;
        #pragma unroll
        for (int q = 0; q < 8; ++q) {
            int i = wave * 8 + q;
            glds16(wp + i * 1024 + lane * 16, Bb + i * 1024);
        }
    }
    {   // write A(0) into buf0 (waits on af[0] loads)
        char* Ab = lds;
        short8 s0, s1;
        #pragma unroll
        for (int e = 0; e < 8; ++e) { s0[e] = (short)f2bf(af[0][e]); s1[e] = (short)f2bf(af[0][8 + e]); }
        *(short8*)(Ab + ((akq * 2) * 64 + arow) * 16) = s0;
        *(short8*)(Ab + ((akq * 2 + 1) * 64 + arow) * 16) = s1;
    }
    #pragma unroll
    for (int q = 0; q < 4; ++q)
        *(float4*)&af[1][q * 4] = *(const float4*)(aptr + 64 + q * 4);

    int cur = 0;
    for (int t = 0; t < NT; ++t) {
        __syncthreads();   // staging of tile t complete (ds_writes + global_load_lds)
        const int nxt = cur ^ 1;
        if (t + 1 < NT) {
            const char* wp = Wpack + (size_t)(t + 1) * 32768;
            char* Bn = lds + 16384 + nxt * 32768;
            #pragma unroll
            for (int q = 0; q < 8; ++q) {
                int i = wave * 8 + q;
                glds16(wp + i * 1024 + lane * 16, Bn + i * 1024);
            }
            char* An = lds + nxt * 8192;
            const float* f = af[(t + 1) & 1];
            short8 s0, s1;
            #pragma unroll
            for (int e = 0; e < 8; ++e) { s0[e] = (short)f2bf(f[e]); s1[e] = (short)f2bf(f[8 + e]); }
            *(short8*)(An + ((akq * 2) * 64 + arow) * 16) = s0;
            *(short8*)(An + ((akq * 2 + 1) * 64 + arow) * 16) = s1;
        }
        if (t + 2 < NT) {
            const float* ap = aptr + (t + 2) * 64;
            #pragma unroll
            for (int q = 0; q < 4; ++q)
                *(float4*)&af[t & 1][q * 4] = *(const float4*)(ap + q * 4);
        }
        // compute tile t from buf cur
        const char* Ab = lds + cur * 8192;
        const char* Bb = lds + 16384 + cur * 32768;
        #pragma unroll
        for (int ks = 0; ks < 4; ++ks) {
            const int chk = ks * 2 + lhi;
            short8 a0 = *(const short8*)(Ab + (chk * 64 + l31) * 16);
            short8 a1 = *(const short8*)(Ab + (chk * 64 + 32 + l31) * 16);
            short8 b0 = *(const short8*)(Bb + (chk * 256 + wcol + l31) * 16);
            short8 b1 = *(const short8*)(Bb + (chk * 256 + wcol + 32 + l31) * 16);
            acc[0][0] = __builtin_amdgcn_mfma_f32_32x32x16_bf16(a0, b0, acc[0][0], 0, 0, 0);
            acc[0][1] = __builtin_amdgcn_mfma_f32_32x32x16_bf16(a0, b1, acc[0][1], 0, 0, 0);
            acc[1][0] = __builtin_amdgcn_mfma_f32_32x32x16_bf16(a1, b0, acc[1][0], 0, 0, 0);
            acc[1][1] = __builtin_amdgcn_mfma_f32_32x32x16_bf16(a1, b1, acc[1][1], 0, 0, 0);
        }
        cur = nxt;
    }

    // epilogue: C layout col=lane&31, row=(r&3)+8*(r>>2)+4*(lane>>5)
    #pragma unroll
    for (int ni = 0; ni < 2; ++ni) {
        int col = wcol + ni * 32 + l31;
        if (col < NBINS) {
            float bias = bvec[col];
            #pragma unroll
            for (int mi = 0; mi < 2; ++mi) {
                #pragma unroll
                for (int r = 0; r < 16; ++r) {
                    int row = row0 + mi * 32 + (r & 3) + 8 * (r >> 2) + 4 * lhi;
                    logits[(size_t)row * NBINS + col] = acc[mi][ni][r] + bias;
                }
            }
        }
    }
}

// per-row softmax stats: value = softmax(l)@centers, logZ
__global__ __launch_bounds__(256) void softmax_stats(
    const float* __restrict__ logits, float* __restrict__ values,
    float* __restrict__ logZ, int R)
{
    int row  = blockIdx.x * 4 + (threadIdx.x >> 6);
    int lane = threadIdx.x & 63;
    if (row >= R) return;
    const float* lp = logits + (size_t)row * NBINS;
    const float step = (float)(40.0 / 254.0);

    float l[4];
    float m = -INFINITY;
    #pragma unroll
    for (int u = 0; u < 4; ++u) {
        int idx = lane + 64 * u;
        l[u] = (idx < NBINS) ? lp[idx] : -INFINITY;
        m = fmaxf(m, l[u]);
    }
    #pragma unroll
    for (int sh = 32; sh >= 1; sh >>= 1) m = fmaxf(m, __shfl_xor(m, sh, 64));

    float s = 0.f, sc = 0.f;
    #pragma unroll
    for (int u = 0; u < 4; ++u) {
        int idx = lane + 64 * u;
        if (idx < NBINS) {
            float e = __expf(l[u] - m);
            s  += e;
            sc += e * (BIN_LO_F + step * (float)idx);
        }
    }
    #pragma unroll
    for (int sh = 32; sh >= 1; sh >>= 1) {
        s  += __shfl_xor(s, sh, 64);
        sc += __shfl_xor(sc, sh, 64);
    }
    if (lane == 0) {
        values[row] = sc / s;
        logZ[row]   = m + __logf(s);
    }
}

__global__ void lambda_returns_k(
    const float* __restrict__ rewards, const float* __restrict__ dones,
    const float* __restrict__ values, float* __restrict__ returns,
    int B, int H, int NR)
{
    int b = blockIdx.x * blockDim.x + threadIdx.x;
    if (b >= B) return;
    const float gamma = 0.997f;
    const float lam   = 0.95f;
    const float oml   = (float)(1.0 - 0.95);
    float bootv = values[NR + b];
    float g = bootv;
    for (int h = H - 1; h >= 0; --h) {
        float nv   = (h == H - 1) ? bootv : values[b * H + h + 1];
        float mask = 1.0f - dones[b * H + h];
        g = rewards[b * H + h] + gamma * mask * (oml * nv + lam * g);
        returns[b * H + h] = g;
    }
}

__global__ __launch_bounds__(256) void loss_moments(
    const float* __restrict__ logits, const float* __restrict__ logZ,
    const float* __restrict__ values, const float* __restrict__ returns,
    double* __restrict__ accum, int NR)
{
    int row = blockIdx.x * blockDim.x + threadIdx.x;
    double lsum = 0, vsum = 0, v2 = 0, rsum = 0, r2 = 0;
    if (row < NR) {
        float v   = values[row];
        float ret = returns[row];
        float cl  = fminf(fmaxf(ret, BIN_LO_F), BIN_HI_F);
        const float step = (float)(40.0 / 254.0);
        float pos = (cl - BIN_LO_F) / step;
        int low = (int)floorf(pos);
        low = min(max(low, 0), NBINS - 2);
        float frac = pos - (float)low;
        const float* lp = logits + (size_t)row * NBINS;
        float llo = lp[low], lhi = lp[low + 1];
        float loss = logZ[row] - (1.f - frac) * llo - frac * lhi;
        lsum = (double)loss;
        vsum = (double)v;   v2 = (double)v * (double)v;
        rsum = (double)ret; r2 = (double)ret * (double)ret;
    }
    lsum = wave_reduce_sum_d(lsum);
    vsum = wave_reduce_sum_d(vsum);
    v2   = wave_reduce_sum_d(v2);
    rsum = wave_reduce_sum_d(rsum);
    r2   = wave_reduce_sum_d(r2);
    if ((threadIdx.x & 63) == 0) {
        atomicAdd(&accum[0], lsum);
        atomicAdd(&accum[1], vsum);
        atomicAdd(&accum[2], v2);
        atomicAdd(&accum[3], rsum);
        atomicAdd(&accum[4], r2);
    }
}

__global__ void finalize_k(const double* __restrict__ accum,
                           float* __restrict__ out, int NR)
{
    if (threadIdx.x == 0 && blockIdx.x == 0) {
        double n  = (double)NR;
        double vl = accum[0] / n;
        double mv = accum[1] / n;
        double vv = (accum[2] - n * mv * mv) / (n - 1.0);
        double mr = accum[3] / n;
        double vr = (accum[4] - n * mr * mr) / (n - 1.0);
        out[0] = (float)(0.5 * vl);
        out[1] = (float)vl;
        out[2] = (float)mv;
        out[3] = (float)mr;
        out[4] = (float)sqrt(vv > 0.0 ? vv : 0.0);
        out[5] = (float)sqrt(vr > 0.0 ? vr : 0.0);
    }
}

extern "C" void kernel_launch(void* const* d_in, const int* in_sizes, int n_in,
                              void* d_out, int out_size, void* d_ws, size_t ws_size,
                              hipStream_t stream) {
    const float* latents = (const float*)d_in[0];
    const float* rewards = (const float*)d_in[1];
    const float* dones   = (const float*)d_in[2];
    const float* boot    = (const float*)d_in[3];
    const float* W       = (const float*)d_in[4];
    const float* bvec    = (const float*)d_in[5];
    float* out = (float*)d_out;

    const int BH = in_sizes[1];          // B*H = 16384
    const int D  = in_sizes[0] / BH;     // 4096
    const int B  = in_sizes[3] / D;      // 1024
    const int H  = BH / B;               // 16
    const int NR = BH;
    const int R  = NR + B;               // 17408

    char* ws = (char*)d_ws;
    size_t off = 0;
    float* logits = (float*)(ws + off); off += (size_t)R * NBINS * sizeof(float);
    off = (off + 255) & ~(size_t)255;
    float* values = (float*)(ws + off); off += (size_t)R * sizeof(float);
    float* logZ   = (float*)(ws + off); off += (size_t)R * sizeof(float);
    float* rets   = (float*)(ws + off); off += (size_t)NR * sizeof(float);
    off = (off + 255) & ~(size_t)255;
    double* accum = (double*)(ws + off); off += 64;
    off = (off + 255) & ~(size_t)255;
    char* Wpack   = ws + off; off += (size_t)(D / 64) * 32768;

    hipMemsetAsync(accum, 0, 64, stream);

    const int packThreads = (D / 64) * 8 * 256;     // one short8 per thread
    pack_w<<<packThreads / 256, 256, 0, stream>>>(W, Wpack);
    gemm_mfma<<<R / 64, 256, 0, stream>>>(latents, boot, Wpack, bvec, logits, NR, R, D);
    softmax_stats<<<(R + 3) / 4, 256, 0, stream>>>(logits, values, logZ, R);
    lambda_returns_k<<<(B + 255) / 256, 256, 0, stream>>>(rewards, dones, values, rets, B, H, NR);
    loss_moments<<<(NR + 255) / 256, 256, 0, stream>>>(logits, logZ, values, rets, accum, NR);
    finalize_k<<<1, 64, 0, stream>>>(accum, out, NR);
}